// Round 23
// baseline (74.248 us; speedup 1.0000x reference)
//
#include <hip/hip_runtime.h>

#define LOG2E 1.4426950408889634f
#define TWO_LOG2E 2.885390081777927f

__device__ __forceinline__ float fast_exp2(float x) { return __builtin_amdgcn_exp2f(x); }
__device__ __forceinline__ float fast_rcp(float x)  { return __builtin_amdgcn_rcpf(x); }

// paired-rcp: s0/A + s1/B with A=q0*k0+1, B=q1*k1+1
__device__ __forceinline__ void term2(float s0, float s1, float qx, float qy,
                                      float kx, float ky, float& acc) {
    const float A = fmaf(qx, kx, 1.f);
    const float B = fmaf(qy, ky, 1.f);
    acc = fmaf(fmaf(s1, A, s0 * B), fast_rcp(A * B), acc);
}

// ---------------------------------------------------------------------------
// K1: projections + exp transform. Blocks 0..255: eq[2048][256] (row-major).
// Blocks 256..511: ekT[b][256 d][512 k] TRANSPOSED.
// ---------------------------------------------------------------------------
__global__ __launch_bounds__(256) void proj_kernel(
    const float* __restrict__ query, const float* __restrict__ value,
    const float* __restrict__ Wq, const float* __restrict__ Wv,
    float* __restrict__ eq, float* __restrict__ ekT)
{
    __shared__ float in_lds[8 * 256];
    const int t = threadIdx.x;
    const int row0 = blockIdx.x * 8;
    const float* src; const float* W;
    if (row0 < 2048) { src = query + (size_t)row0 * 256; W = Wq; }
    else { src = value + (size_t)(row0 - 2048) * 256; W = Wv; }

    const float4* s4 = (const float4*)src;
    float4* l4 = (float4*)in_lds;
    l4[t] = s4[t];
    l4[t + 256] = s4[t + 256];
    __syncthreads();

    float acc[8];
#pragma unroll
    for (int r = 0; r < 8; ++r) acc[r] = 0.f;

    for (int d = 0; d < 256; d += 4) {
        const float w0 = W[(d + 0) * 256 + t];
        const float w1 = W[(d + 1) * 256 + t];
        const float w2 = W[(d + 2) * 256 + t];
        const float w3 = W[(d + 3) * 256 + t];
#pragma unroll
        for (int r = 0; r < 8; ++r) {
            const float4 v = *(const float4*)&in_lds[r * 256 + d];
            acc[r] = fmaf(v.x, w0, acc[r]);
            acc[r] = fmaf(v.y, w1, acc[r]);
            acc[r] = fmaf(v.z, w2, acc[r]);
            acc[r] = fmaf(v.w, w3, acc[r]);
        }
    }

    if (row0 < 2048) {
        float* dst = eq + (size_t)row0 * 256;
#pragma unroll
        for (int r = 0; r < 8; ++r) dst[r * 256 + t] = fast_exp2(acc[r] * TWO_LOG2E);
    } else {
        const int r0 = row0 - 2048;
        const int bb = r0 >> 9, kin = r0 & 511;
        float* dstT = ekT + (size_t)bb * 131072 + (size_t)t * 512 + kin;
        float4 v0, v1;
        v0.x = fast_exp2(acc[0] * TWO_LOG2E); v0.y = fast_exp2(acc[1] * TWO_LOG2E);
        v0.z = fast_exp2(acc[2] * TWO_LOG2E); v0.w = fast_exp2(acc[3] * TWO_LOG2E);
        v1.x = fast_exp2(acc[4] * TWO_LOG2E); v1.y = fast_exp2(acc[5] * TWO_LOG2E);
        v1.z = fast_exp2(acc[6] * TWO_LOG2E); v1.w = fast_exp2(acc[7] * TWO_LOG2E);
        *(float4*)dstT = v0;
        *(float4*)(dstT + 4) = v1;
    }
}

// ---------------------------------------------------------------------------
// K2: FUSED scores + softmax + PV, v10 = v9 structure at 2 blocks/CU.
// Block = (b, 4 q-rows), 512 thr (8 waves), grid (128,4) = 512 blocks
// -> 16 waves/CU (4/SIMD), ~30KB LDS/block. No barriers in scores; blocks
// independent -> latency stalls in one overlap compute in the other.
// Thread = (qg = w>>2: 2 q-rows, kg = (w&3)*64+lane: 2 k-cols), full 256 d,
// depth-1 software pipeline (proven v9: VGPR 88, 0 conflicts).
// ---------------------------------------------------------------------------
#define EQ_ST 260
#define SS_ST 520
__global__ __launch_bounds__(512, 4) void fused_kernel(
    const float* __restrict__ eq, const float* __restrict__ ekT,
    const float* __restrict__ scale, const float* __restrict__ value,
    float* __restrict__ attn, float* __restrict__ out)
{
    __shared__ float eq_lds[4 * EQ_ST];     // 4.2KB
    __shared__ float sc_lds[256];
    __shared__ float s_tile[4 * SS_ST];     // 8.3KB raw scores -> raw exp
    __shared__ float red[4 * 4 * 256];      // 16KB PV reduce buffer
    __shared__ float inv_lds[4];

    const int t = threadIdx.x;
    const int w = t >> 6, lane = t & 63;
    const int qg = w >> 2;                  // 0..1 (2 q-rows each)
    const int kg = ((w & 3) << 6) + lane;   // 0..255 (2 k-cols each)
    const int k0 = 2 * kg;
    const int qt = blockIdx.x, b = blockIdx.y;
    const int q0 = qt * 4;

    // prologue: stage eq (4x256 = 256 float4s) and scale
    if (t < 256) {
        const int row = t >> 6, c = t & 63;
        const float4 v = ((const float4*)(eq + (size_t)(b * 512 + q0) * 256))[t];
        *(float4*)&eq_lds[row * EQ_ST + 4 * c] = v;
    } else {
        sc_lds[t - 256] = -2.f * scale[t - 256];
    }
    __syncthreads();

    // ---- Phase A: scores, full d per thread, NO barriers, pipelined ----
    const float* ekTb = ekT + (size_t)b * 131072;
    const float* q0r = &eq_lds[(2 * qg + 0) * EQ_ST];
    const float* q1r = &eq_lds[(2 * qg + 1) * EQ_ST];

    float a00 = 0.f, a01 = 0.f, a10 = 0.f, a11 = 0.f;

    // preload iteration d=0
    float4 sv  = *(const float4*)&sc_lds[0];
    float4 qv0 = *(const float4*)&q0r[0];
    float4 qv1 = *(const float4*)&q1r[0];
    float2 k0v = *(const float2*)&ekTb[(size_t)0 * 512 + k0];
    float2 k1v = *(const float2*)&ekTb[(size_t)1 * 512 + k0];
    float2 k2v = *(const float2*)&ekTb[(size_t)2 * 512 + k0];
    float2 k3v = *(const float2*)&ekTb[(size_t)3 * 512 + k0];

#pragma unroll 4
    for (int d = 0; d < 256; d += 4) {
        const float4 csv = sv, c0 = qv0, c1 = qv1;
        const float2 ck0 = k0v, ck1 = k1v, ck2 = k2v, ck3 = k3v;

        if (d < 252) {                      // prefetch iteration d+4
            const int dn = d + 4;
            sv  = *(const float4*)&sc_lds[dn];
            qv0 = *(const float4*)&q0r[dn];
            qv1 = *(const float4*)&q1r[dn];
            k0v = *(const float2*)&ekTb[(size_t)(dn + 0) * 512 + k0];
            k1v = *(const float2*)&ekTb[(size_t)(dn + 1) * 512 + k0];
            k2v = *(const float2*)&ekTb[(size_t)(dn + 2) * 512 + k0];
            k3v = *(const float2*)&ekTb[(size_t)(dn + 3) * 512 + k0];
        }

        // pairs (d,d+1) and (d+2,d+3); k-col 0 -> .x, k-col 1 -> .y
        term2(csv.x, csv.y, c0.x, c0.y, ck0.x, ck1.x, a00);
        term2(csv.z, csv.w, c0.z, c0.w, ck2.x, ck3.x, a00);
        term2(csv.x, csv.y, c0.x, c0.y, ck0.y, ck1.y, a01);
        term2(csv.z, csv.w, c0.z, c0.w, ck2.y, ck3.y, a01);

        term2(csv.x, csv.y, c1.x, c1.y, ck0.x, ck1.x, a10);
        term2(csv.z, csv.w, c1.z, c1.w, ck2.x, ck3.x, a10);
        term2(csv.x, csv.y, c1.x, c1.y, ck0.y, ck1.y, a11);
        term2(csv.z, csv.w, c1.z, c1.w, ck2.y, ck3.y, a11);
    }

    // write raw scores (float2 per q-row; lanes 8B apart -> 2-way banks, free)
    *(float2*)&s_tile[(2 * qg + 0) * SS_ST + k0] = make_float2(a00, a01);
    *(float2*)&s_tile[(2 * qg + 1) * SS_ST + k0] = make_float2(a10, a11);
    __syncthreads();

    // ---- Phase B: softmax (waves 0..3, wave = q-row), attn write ----
    if (w < 4) {
        float x[8];
        float m = -1e30f;
#pragma unroll
        for (int j = 0; j < 8; ++j) {
            x[j] = s_tile[w * SS_ST + 64 * j + lane];
            m = fmaxf(m, x[j]);
        }
#pragma unroll
        for (int off = 32; off; off >>= 1) m = fmaxf(m, __shfl_xor(m, off));

        float sum = 0.f;
#pragma unroll
        for (int j = 0; j < 8; ++j) { x[j] = fast_exp2((x[j] - m) * LOG2E); sum += x[j]; }
#pragma unroll
        for (int off = 32; off; off >>= 1) sum += __shfl_xor(sum, off);
        const float inv = fast_rcp(sum);

        float* arow = attn + (size_t)(b * 512 + q0 + w) * 512;
#pragma unroll
        for (int j = 0; j < 8; ++j) {
            s_tile[w * SS_ST + 64 * j + lane] = x[j];   // raw exp for PV
            arow[64 * j + lane] = x[j] * inv;
        }
        if (lane == 0) inv_lds[w] = inv;
    }
    __syncthreads();

    // ---- Phase C: PV, wave w owns k in [64w, 64w+64) ----
    float4 acc[4];
#pragma unroll
    for (int r = 0; r < 4; ++r) acc[r] = make_float4(0.f, 0.f, 0.f, 0.f);

    const float* vbase = value + (size_t)(b * 512 + 64 * w) * 256;
    for (int k4 = 0; k4 < 64; k4 += 4) {
        const float4 v0 = *(const float4*)&vbase[(k4 + 0) * 256 + lane * 4];
        const float4 v1 = *(const float4*)&vbase[(k4 + 1) * 256 + lane * 4];
        const float4 v2 = *(const float4*)&vbase[(k4 + 2) * 256 + lane * 4];
        const float4 v3 = *(const float4*)&vbase[(k4 + 3) * 256 + lane * 4];
#pragma unroll
        for (int r = 0; r < 4; ++r) {
            const float4 s4 = *(const float4*)&s_tile[r * SS_ST + 64 * w + k4];
            acc[r].x = fmaf(s4.x, v0.x, acc[r].x); acc[r].y = fmaf(s4.x, v0.y, acc[r].y);
            acc[r].z = fmaf(s4.x, v0.z, acc[r].z); acc[r].w = fmaf(s4.x, v0.w, acc[r].w);
            acc[r].x = fmaf(s4.y, v1.x, acc[r].x); acc[r].y = fmaf(s4.y, v1.y, acc[r].y);
            acc[r].z = fmaf(s4.y, v1.z, acc[r].z); acc[r].w = fmaf(s4.y, v1.w, acc[r].w);
            acc[r].x = fmaf(s4.z, v2.x, acc[r].x); acc[r].y = fmaf(s4.z, v2.y, acc[r].y);
            acc[r].z = fmaf(s4.z, v2.z, acc[r].z); acc[r].w = fmaf(s4.z, v2.w, acc[r].w);
            acc[r].x = fmaf(s4.w, v3.x, acc[r].x); acc[r].y = fmaf(s4.w, v3.y, acc[r].y);
            acc[r].z = fmaf(s4.w, v3.z, acc[r].z); acc[r].w = fmaf(s4.w, v3.w, acc[r].w);
        }
    }

    // ---- Phase D: tree reduce 8 -> 1 ----
    if (w >= 4) {
#pragma unroll
        for (int r = 0; r < 4; ++r)
            *(float4*)&red[((w - 4) * 4 + r) * 256 + lane * 4] = acc[r];
    }
    __syncthreads();
    if (w < 4) {
#pragma unroll
        for (int r = 0; r < 4; ++r) {
            const float4 o = *(const float4*)&red[(w * 4 + r) * 256 + lane * 4];
            acc[r].x += o.x; acc[r].y += o.y; acc[r].z += o.z; acc[r].w += o.w;
        }
    }
    __syncthreads();
    if (w >= 2 && w < 4) {
#pragma unroll
        for (int r = 0; r < 4; ++r)
            *(float4*)&red[((w - 2) * 4 + r) * 256 + lane * 4] = acc[r];
    }
    __syncthreads();
    if (w < 2) {
#pragma unroll
        for (int r = 0; r < 4; ++r) {
            const float4 o = *(const float4*)&red[(w * 4 + r) * 256 + lane * 4];
            acc[r].x += o.x; acc[r].y += o.y; acc[r].z += o.z; acc[r].w += o.w;
        }
    }
    __syncthreads();
    if (w == 1) {
#pragma unroll
        for (int r = 0; r < 4; ++r)
            *(float4*)&red[r * 256 + lane * 4] = acc[r];
    }
    __syncthreads();
    if (w == 0) {
#pragma unroll
        for (int r = 0; r < 4; ++r) {
            const float4 o = *(const float4*)&red[r * 256 + lane * 4];
            const float iv = inv_lds[r];
            float4 res;
            res.x = (acc[r].x + o.x) * iv;
            res.y = (acc[r].y + o.y) * iv;
            res.z = (acc[r].z + o.z) * iv;
            res.w = (acc[r].w + o.w) * iv;
            *(float4*)&out[(size_t)(b * 512 + q0 + r) * 256 + lane * 4] = res;
        }
    }
}

extern "C" void kernel_launch(void* const* d_in, const int* in_sizes, int n_in,
                              void* d_out, int out_size, void* d_ws, size_t ws_size,
                              hipStream_t stream) {
    const float* query = (const float*)d_in[0];
    const float* value = (const float*)d_in[1];
    const float* Wq    = (const float*)d_in[2];
    const float* Wv    = (const float*)d_in[3];
    const float* scale = (const float*)d_in[4];

    float* out0 = (float*)d_out;                 // [4,512,256]
    float* attn = out0 + 4 * 512 * 256;          // [4,512,512]

    float* eq  = (float*)d_ws;                   // [2048,256]
    float* ekT = eq + 2048 * 256;                // [4,256,512] transposed

    proj_kernel<<<512, 256, 0, stream>>>(query, value, Wq, Wv, eq, ekT);
    fused_kernel<<<dim3(128, 4), 512, 0, stream>>>(eq, ekT, scale, value, attn, out0);
}